// Round 8
// baseline (391.882 us; speedup 1.0000x reference)
//
#include <hip/hip_runtime.h>
#include <hip/hip_bf16.h>
#include <cstddef>
#include <cstdint>

#define N_NODES 100000
#define N_ROWS  100032            // padded to 32-row tiles
#define DUMMY   100000            // zeroed pad row in feature buffers
#define N_EDGES 1600000
#define N_REL   4
#define N_BASES 30
#define FIN     86
#define HID     128
#define N_CLS   18
#define N_GRAPH 512
#define KCAT    640               // 4 relation blocks + root block, 128 each
#define BM      32                // rows per fused block
#define NKK     (KCAT / 32)       // 20 K-steps

#define SEG (N_REL * N_NODES)                         // 400000 segments
#define SSRC_MAX (N_EDGES + 3 * SEG)                  // padded CSR worst case
#define SCAN_CHUNK 1024
#define NB_SCAN ((SEG + SCAN_CHUNK - 1) / SCAN_CHUNK) // 391

typedef __attribute__((ext_vector_type(8))) short bf16x8;
typedef __attribute__((ext_vector_type(4))) float f32x4;

__device__ inline float blo(unsigned int u) {
    union { unsigned int i; float f; } c; c.i = u << 16; return c.f;
}
__device__ inline float bhi(unsigned int u) {
    union { unsigned int i; float f; } c; c.i = u & 0xffff0000u; return c.f;
}
__device__ inline unsigned short f2bf(float f) {
    __hip_bfloat16 h = __float2bfloat16(f);
    return *reinterpret_cast<unsigned short*>(&h);
}
__device__ inline unsigned int pk2(float lo, float hi) {
    return (unsigned int)f2bf(lo) | ((unsigned int)f2bf(hi) << 16);
}
__device__ inline int pad4i(int x) { return (x + 3) & ~3; }

// Stacked transposed weights: Wt[n][s], s = r*128+k (r<4: sum_b comp*basis) or 512+k (root).
template <int KV>
__global__ void k_wt(const float* __restrict__ basis, const float* __restrict__ comp,
                     const float* __restrict__ root, short* __restrict__ Wt) {
    int id = blockIdx.x * 256 + threadIdx.x;
    if (id >= KCAT * HID) return;
    int n = id & 127, s = id >> 7;
    int k = s & 127, blk = s >> 7;
    float v = 0.f;
    if (k < KV) {
        if (blk < N_REL) {
#pragma unroll
            for (int b = 0; b < N_BASES; ++b)
                v += comp[blk * N_BASES + b] * basis[((size_t)b * KV + k) * HID + n];
        } else {
            v = root[k * HID + n];
        }
    }
    Wt[(size_t)n * KCAT + s] = (short)f2bf(v);
}

// x[N,86] f32 -> X0[N_ROWS][128] bf16 (zero pad rows/cols); zero H1 pad rows (incl DUMMY)
__global__ void k_xcvt(const float* __restrict__ x, short* __restrict__ X0,
                       short* __restrict__ H1) {
    int id = blockIdx.x * 256 + threadIdx.x;
    if (id >= N_ROWS * HID) return;
    int n = id >> 7, k = id & 127;
    float v = (n < N_NODES && k < FIN) ? x[n * FIN + k] : 0.f;
    X0[id] = (short)f2bf(v);
    if (n >= N_NODES) H1[id] = 0;
}

// prefill padded CSR with DUMMY
__global__ void k_fill(int* __restrict__ p) {
    int i = blockIdx.x * 256 + threadIdx.x;
    if (i < SSRC_MAX) p[i] = DUMMY;
}

// histogram + per-edge rank in one atomic pass
__global__ void k_count(const int* __restrict__ et, const int* __restrict__ dst,
                        int* __restrict__ cnt, int* __restrict__ rank) {
    int e = blockIdx.x * 256 + threadIdx.x;
    if (e >= N_EDGES) return;
    rank[e] = atomicAdd(cnt + et[e] * N_NODES + dst[e], 1);
}

// ---- scan of pad4(cnt[SEG]) -> off[SEG] ----
__global__ void k_bsum(const int* __restrict__ cnt, int* __restrict__ bsum) {
    __shared__ int red[256];
    int base = blockIdx.x * SCAN_CHUNK + threadIdx.x * 4;
    int s = 0;
#pragma unroll
    for (int j = 0; j < 4; j++) { int idx = base + j; if (idx < SEG) s += pad4i(cnt[idx]); }
    red[threadIdx.x] = s;
    __syncthreads();
    for (int w = 128; w > 0; w >>= 1) {
        if (threadIdx.x < w) red[threadIdx.x] += red[threadIdx.x + w];
        __syncthreads();
    }
    if (threadIdx.x == 0) bsum[blockIdx.x] = red[0];
}

// parallel single-block exclusive scan of bsum (NB_SCAN < 512)
__global__ void k_bpref(int* __restrict__ bsum, int nb) {
    __shared__ int s[512];
    int t = threadIdx.x;
    int v = (t < nb) ? bsum[t] : 0;
    s[t] = v;
    __syncthreads();
    for (int d = 1; d < 512; d <<= 1) {
        int add = (t >= d) ? s[t - d] : 0;
        __syncthreads();
        s[t] += add;
        __syncthreads();
    }
    if (t < nb) bsum[t] = s[t] - v;
}

__global__ void k_offsets(const int* __restrict__ cnt, const int* __restrict__ bpref,
                          int* __restrict__ off) {
    __shared__ int tp[256];
    int t = threadIdx.x;
    int base = blockIdx.x * SCAN_CHUNK + t * 4;
    int v[4], s = 0;
#pragma unroll
    for (int j = 0; j < 4; j++) { int idx = base + j; v[j] = (idx < SEG) ? pad4i(cnt[idx]) : 0; s += v[j]; }
    tp[t] = s;
    __syncthreads();
    if (t == 0) { int run = 0; for (int i = 0; i < 256; i++) { int x = tp[i]; tp[i] = run; run += x; } }
    __syncthreads();
    int p = bpref[blockIdx.x] + tp[t];
#pragma unroll
    for (int j = 0; j < 4; j++) { int idx = base + j; if (idx < SEG) off[idx] = p; p += v[j]; }
}

// atomic-free scatter using precomputed rank (pad slots keep DUMMY)
__global__ void k_scatter(const int* __restrict__ et, const int* __restrict__ srcI,
                          const int* __restrict__ dstI, const int* __restrict__ off,
                          const int* __restrict__ rank, int* __restrict__ ssrc) {
    int e = blockIdx.x * 256 + threadIdx.x;
    if (e >= N_EDGES) return;
    int seg = et[e] * N_NODES + dstI[e];
    ssrc[off[seg] + rank[e]] = srcI[e];
}

// ===== fused agg+GEMM: one 32-row M-tile per block, 512 thr (8 waves) =====
// LDS A-tile As[32][640] bf16, XOR-swizzled (byte ^ ((row&7)<<4)).
//  phase 1: stage root block (cols 512..639) from F rows m0.. (1 uint4/thread)
//  phase 2: 32 groups x 16 lanes gather per-(node,rel) means straight into LDS
//  phase 3: B (Wt slice, 16 cols/wave) in 80 VGPRs; 40 ds_read_b128 + 40 MFMA/wave
//  epilogue: MODE 1 relu(.+bias)->H; MODE 2 run-compressed pool atomics into g
template <int MODE>
__launch_bounds__(512, 4)
__global__ void k_fused(const short* __restrict__ F,
                        const int* __restrict__ off, const int* __restrict__ cnt,
                        const int* __restrict__ ssrc,
                        const short* __restrict__ Wt,
                        const float* __restrict__ bias,
                        short* __restrict__ H,
                        const int* __restrict__ batch, float* __restrict__ g) {
    __shared__ short As[BM * KCAT];                 // 40960 B
    char* Ab = reinterpret_cast<char*>(As);
    const int tid = threadIdx.x;
    const int m0 = blockIdx.x * BM;

    // ---- phase 1: root block cols [512,640)
    {
        const int row = tid >> 4, cu = tid & 15;
        uint4 v = *reinterpret_cast<const uint4*>(F + (size_t)(m0 + row) * HID + cu * 8);
        const int p = (row * 1280 + 1024 + cu * 16) ^ ((row & 7) << 4);
        *reinterpret_cast<uint4*>(Ab + p) = v;
    }

    // ---- phase 2: relation means cols [0,512)
    {
        const int G = tid >> 4, q = tid & 15;
        const int node = m0 + G;
        if (node < N_NODES) {
            const int pbase = G * 1280 + q * 16;
            const int swz = (G & 7) << 4;
            for (int r = 0; r < N_REL; ++r) {
                const int seg = r * N_NODES + node;
                const int o0 = off[seg], c = cnt[seg];
                float a[8];
#pragma unroll
                for (int j = 0; j < 8; ++j) a[j] = 0.f;
                const int4* sp = reinterpret_cast<const int4*>(ssrc + o0);
                const int nch = (c + 3) >> 2;
                for (int ch = 0; ch < nch; ++ch) {
                    int4 e4 = sp[ch];
                    uint4 v0 = *reinterpret_cast<const uint4*>(F + (size_t)e4.x * HID + q * 8);
                    uint4 v1 = *reinterpret_cast<const uint4*>(F + (size_t)e4.y * HID + q * 8);
                    uint4 v2 = *reinterpret_cast<const uint4*>(F + (size_t)e4.z * HID + q * 8);
                    uint4 v3 = *reinterpret_cast<const uint4*>(F + (size_t)e4.w * HID + q * 8);
                    a[0] += blo(v0.x) + blo(v1.x) + blo(v2.x) + blo(v3.x);
                    a[1] += bhi(v0.x) + bhi(v1.x) + bhi(v2.x) + bhi(v3.x);
                    a[2] += blo(v0.y) + blo(v1.y) + blo(v2.y) + blo(v3.y);
                    a[3] += bhi(v0.y) + bhi(v1.y) + bhi(v2.y) + bhi(v3.y);
                    a[4] += blo(v0.z) + blo(v1.z) + blo(v2.z) + blo(v3.z);
                    a[5] += bhi(v0.z) + bhi(v1.z) + bhi(v2.z) + bhi(v3.z);
                    a[6] += blo(v0.w) + blo(v1.w) + blo(v2.w) + blo(v3.w);
                    a[7] += bhi(v0.w) + bhi(v1.w) + bhi(v2.w) + bhi(v3.w);
                }
                const float inv = (c > 0) ? 1.f / (float)c : 0.f;
                uint4 w;
                w.x = pk2(a[0] * inv, a[1] * inv);
                w.y = pk2(a[2] * inv, a[3] * inv);
                w.z = pk2(a[4] * inv, a[5] * inv);
                w.w = pk2(a[6] * inv, a[7] * inv);
                *reinterpret_cast<uint4*>(Ab + ((pbase + r * 256) ^ swz)) = w;
            }
        }
    }
    __syncthreads();

    // ---- phase 3: B in registers, MFMA over K=640
    const int wave = tid >> 6, lane = tid & 63;
    const int q = lane & 15, hi = lane >> 4;
    const int col = wave * 16 + q;

    bf16x8 bfrag[NKK];
    {
        const short* bp = Wt + (size_t)col * KCAT + hi * 8;
#pragma unroll
        for (int kk = 0; kk < NKK; ++kk)
            bfrag[kk] = *reinterpret_cast<const bf16x8*>(bp + kk * 32);
    }

    f32x4 acc[2];
    acc[0] = (f32x4){0.f, 0.f, 0.f, 0.f};
    acc[1] = (f32x4){0.f, 0.f, 0.f, 0.f};
    const int arow = q * 1280;
    const int bx = (hi * 16) ^ ((q & 7) << 4);
#pragma unroll
    for (int kk = 0; kk < NKK; ++kk) {
        const int bo = (kk * 64) ^ bx;
#pragma unroll
        for (int rf = 0; rf < 2; ++rf) {
            bf16x8 a = *reinterpret_cast<const bf16x8*>(Ab + arow + rf * (16 * 1280) + bo);
            acc[rf] = __builtin_amdgcn_mfma_f32_16x16x32_bf16(a, bfrag[kk], acc[rf], 0, 0, 0);
        }
    }

    // ---- epilogue
    if (MODE == 1) {
        const float bc = bias[col];
#pragma unroll
        for (int rf = 0; rf < 2; ++rf) {
#pragma unroll
            for (int r = 0; r < 4; ++r) {
                const int row = m0 + rf * 16 + hi * 4 + r;
                if (row < N_NODES) {
                    float v = fmaxf(acc[rf][r] + bc, 0.f);
                    H[(size_t)row * HID + col] = (short)f2bf(v);
                }
            }
        }
    } else {
        int curb = -1;
        float run = 0.f;
#pragma unroll
        for (int rf = 0; rf < 2; ++rf) {
#pragma unroll
            for (int r = 0; r < 4; ++r) {
                const int row = m0 + rf * 16 + hi * 4 + r;
                if (row < N_NODES) {
                    int b = batch[row];
                    if (b != curb) {
                        if (curb >= 0) atomicAdd(&g[curb * HID + col], run);
                        curb = b; run = 0.f;
                    }
                    run += acc[rf][r];
                }
            }
        }
        if (curb >= 0) atomicAdd(&g[curb * HID + col], run);
    }
}

// per-graph: pooled = g + cnt*bias2; relu(pooled @ fc_w + fc_b) -> log_softmax
__global__ void k_fc(const float* __restrict__ g, const float* __restrict__ bias2,
                     const int* __restrict__ batch, const float* __restrict__ fcw,
                     const float* __restrict__ fcb, float* __restrict__ out) {
    __shared__ float pooled[HID];
    __shared__ float vals[N_CLS];
    __shared__ float s_lse;
    __shared__ int s_cnt;
    int gi = blockIdx.x, t = threadIdx.x;
    if (t == 0) {
        int lo = 0, hi = N_NODES;
        while (lo < hi) { int m = (lo + hi) >> 1; if (batch[m] < gi) lo = m + 1; else hi = m; }
        int lo2 = lo, hi2 = N_NODES;
        while (lo2 < hi2) { int m = (lo2 + hi2) >> 1; if (batch[m] < gi + 1) lo2 = m + 1; else hi2 = m; }
        s_cnt = lo2 - lo;
    }
    __syncthreads();
    pooled[t] = g[gi * HID + t] + (float)s_cnt * bias2[t];
    __syncthreads();
    if (t < N_CLS) {
        float acc = fcb[t];
        for (int k = 0; k < HID; k++) acc = fmaf(pooled[k], fcw[k * N_CLS + t], acc);
        vals[t] = fmaxf(acc, 0.f);
    }
    __syncthreads();
    if (t == 0) {
        float m = vals[0];
        for (int c = 1; c < N_CLS; c++) m = fmaxf(m, vals[c]);
        float ssum = 0.f;
        for (int c = 0; c < N_CLS; c++) ssum += expf(vals[c] - m);
        s_lse = m + logf(ssum);
    }
    __syncthreads();
    if (t < N_CLS) out[gi * N_CLS + t] = vals[t] - s_lse;
}

extern "C" void kernel_launch(void* const* d_in, const int* in_sizes, int n_in,
                              void* d_out, int out_size, void* d_ws, size_t ws_size,
                              hipStream_t stream) {
    const float* x      = (const float*)d_in[0];
    const int*   ei     = (const int*)d_in[1];
    const int*   src    = ei;
    const int*   dst    = ei + N_EDGES;
    const int*   et     = (const int*)d_in[2];
    const int*   batch  = (const int*)d_in[3];
    const float* basis1 = (const float*)d_in[4];
    const float* comp1  = (const float*)d_in[5];
    const float* root1  = (const float*)d_in[6];
    const float* bias1  = (const float*)d_in[7];
    const float* basis2 = (const float*)d_in[8];
    const float* comp2  = (const float*)d_in[9];
    const float* root2  = (const float*)d_in[10];
    const float* bias2  = (const float*)d_in[11];
    const float* fcw    = (const float*)d_in[12];
    const float* fcb    = (const float*)d_in[13];
    float* out = (float*)d_out;

    // workspace layout (~73 MB)
    short* X0   = (short*)d_ws;                        // [N_ROWS][128] bf16
    short* H1   = X0 + (size_t)N_ROWS * HID;           // [N_ROWS][128] bf16
    short* Wt1  = H1 + (size_t)N_ROWS * HID;           // [128][640] bf16
    short* Wt2  = Wt1 + HID * KCAT;                    // [128][640] bf16
    float* g    = (float*)(Wt2 + HID * KCAT);          // [512][128] f32
    int*   cnt  = (int*)(g + N_GRAPH * HID);           // SEG
    int*   off  = cnt + SEG;                           // SEG (padded offsets)
    int*   bsum = off + SEG;                           // 512
    int*   rank = bsum + 512;                          // E
    int*   ssrc = rank + N_EDGES;                      // SSRC_MAX (padded CSR)

    hipMemsetAsync(cnt, 0, SEG * sizeof(int), stream);
    hipMemsetAsync(g, 0, (size_t)N_GRAPH * HID * sizeof(float), stream);

    k_wt<FIN><<<(KCAT * HID + 255) / 256, 256, 0, stream>>>(basis1, comp1, root1, Wt1);
    k_wt<HID><<<(KCAT * HID + 255) / 256, 256, 0, stream>>>(basis2, comp2, root2, Wt2);
    k_xcvt<<<(N_ROWS * HID + 255) / 256, 256, 0, stream>>>(x, X0, H1);
    k_fill<<<(SSRC_MAX + 255) / 256, 256, 0, stream>>>(ssrc);

    // CSR build by (relation, dst): count(+rank) -> padded scan -> scatter
    k_count<<<(N_EDGES + 255) / 256, 256, 0, stream>>>(et, dst, cnt, rank);
    k_bsum<<<NB_SCAN, 256, 0, stream>>>(cnt, bsum);
    k_bpref<<<1, 512, 0, stream>>>(bsum, NB_SCAN);
    k_offsets<<<NB_SCAN, 256, 0, stream>>>(cnt, bsum, off);
    k_scatter<<<(N_EDGES + 255) / 256, 256, 0, stream>>>(et, src, dst, off, rank, ssrc);

    const int FUSED_GRID = N_ROWS / BM;    // 3126

    // layer 1: h1 = relu( [means(x)|x] @ W1stack + bias1 )
    k_fused<1><<<FUSED_GRID, 512, 0, stream>>>(X0, off, cnt, ssrc, Wt1, bias1, H1,
                                               nullptr, nullptr);
    // layer 2: pool( [means(h1)|h1] @ W2stack ) fused; bias2 folded into fc
    k_fused<2><<<FUSED_GRID, 512, 0, stream>>>(H1, off, cnt, ssrc, Wt2, nullptr, nullptr,
                                               batch, g);

    // fc + log_softmax (with bias2 * node-count fold)
    k_fc<<<N_GRAPH, HID, 0, stream>>>(g, bias2, batch, fcw, fcb, out);
}